// Round 1
// baseline (6933.105 us; speedup 1.0000x reference)
//
#include <hip/hip_runtime.h>
#include <math.h>

#define NPTS 8192
#define KNNK 10

__device__ __forceinline__ float preluf(float v, float a){ return v >= 0.f ? v : a*v; }
__device__ __forceinline__ float4 f4fma(float a, float4 b, float4 c){
  return make_float4(fmaf(a,b.x,c.x), fmaf(a,b.y,c.y), fmaf(a,b.z,c.z), fmaf(a,b.w,c.w));
}
__device__ __forceinline__ float4 f4add(float4 a, float4 b){
  return make_float4(a.x+b.x, a.y+b.y, a.z+b.z, a.w+b.w);
}
__device__ __forceinline__ bool lexless(float d1, int i1, float d2, int i2){
  return (d1 < d2) || (d1 == d2 && i1 < i2);
}

// ---------- prep: x0pad (targets padded to 4ch) + sqnorm ----------
__global__ __launch_bounds__(256) void prep0_kernel(const float* __restrict__ T,
                                                    float* __restrict__ x0,
                                                    float* __restrict__ sqn){
  int p = blockIdx.x*256 + threadIdx.x;
  float t0 = T[p*3+0], t1 = T[p*3+1], t2 = T[p*3+2];
  *(float4*)(x0 + (size_t)p*4) = make_float4(t0,t1,t2,0.f);
  float s = fmaf(t0,t0,0.f); s = fmaf(t1,t1,s); s = fmaf(t2,t2,s); s = fmaf(0.f,0.f,s);
  sqn[p] = s;
}

__global__ __launch_bounds__(256) void sqnorm_kernel(const float* __restrict__ XC, int cin,
                                                     float* __restrict__ sqn){
  int p = blockIdx.x*256 + threadIdx.x;
  const float4* r = (const float4*)(XC + (size_t)p*192 + cin);
  float s = 0.f;
  #pragma unroll
  for (int c4=0;c4<16;++c4){
    float4 v = r[c4];
    s = fmaf(v.x,v.x,s); s = fmaf(v.y,v.y,s); s = fmaf(v.z,v.z,s); s = fmaf(v.w,v.w,s);
  }
  sqn[p] = s;
}

// ---------- fused distance-GEMM + top-10 KNN ----------
// block: 256 thr, 128 queries; j-tiles of 256; thread tile 8q x 16j.
// topk: 2 threads per query scan disjoint j-subsets, merge at end.
template<int C>
__global__ __launch_bounds__(256) void knn_kernel(const float* __restrict__ X, int ldx, int coff,
                                                  const float* __restrict__ sqn,
                                                  int* __restrict__ idxout){
  __shared__ __align__(16) float xqT[C][132];
  __shared__ __align__(16) float xjT[C][260];
  __shared__ float s_x2q[128];
  __shared__ float s_x2j[256];
  __shared__ __align__(16) float dch[128][72];

  const int b   = blockIdx.y;
  const int q0  = blockIdx.x * 128;
  const int tid = threadIdx.x;
  const int qg  = tid & 15;
  const int jg  = tid >> 4;
  const int tq  = tid & 127;
  const int th  = tid >> 7;

  const float* Xb = X + (size_t)b * NPTS * ldx + coff;

  for (int i = tid; i < 128*(C/4); i += 256) {
    int r = i / (C/4), c4 = (i % (C/4))*4;
    float4 v = *(const float4*)(Xb + (size_t)(q0+r)*ldx + c4);
    xqT[c4+0][r] = v.x; xqT[c4+1][r] = v.y; xqT[c4+2][r] = v.z; xqT[c4+3][r] = v.w;
  }
  if (tid < 128) s_x2q[tid] = sqn[b*NPTS + q0 + tid];

  float bd[10]; int bi[10];
  #pragma unroll
  for (int u=0;u<10;++u){ bd[u] = INFINITY; bi[u] = 0x7fffffff; }

  for (int j0 = 0; j0 < NPTS; j0 += 256) {
    __syncthreads();
    for (int i = tid; i < 256*(C/4); i += 256) {
      int r = i / (C/4), c4 = (i % (C/4))*4;
      float4 v = *(const float4*)(Xb + (size_t)(j0+r)*ldx + c4);
      xjT[c4+0][r] = v.x; xjT[c4+1][r] = v.y; xjT[c4+2][r] = v.z; xjT[c4+3][r] = v.w;
    }
    s_x2j[tid] = sqn[b*NPTS + j0 + tid];
    __syncthreads();

    float acc[8][16];
    #pragma unroll
    for (int i=0;i<8;++i)
      #pragma unroll
      for (int j=0;j<16;++j) acc[i][j] = 0.f;

    #pragma unroll 4
    for (int c=0;c<C;++c) {
      float aq[8], bj[16];
      *(float4*)&aq[0]  = *(const float4*)&xqT[c][qg*8+0];
      *(float4*)&aq[4]  = *(const float4*)&xqT[c][qg*8+4];
      *(float4*)&bj[0]  = *(const float4*)&xjT[c][jg*16+0];
      *(float4*)&bj[4]  = *(const float4*)&xjT[c][jg*16+4];
      *(float4*)&bj[8]  = *(const float4*)&xjT[c][jg*16+8];
      *(float4*)&bj[12] = *(const float4*)&xjT[c][jg*16+12];
      #pragma unroll
      for (int i=0;i<8;++i)
        #pragma unroll
        for (int j=0;j<16;++j)
          acc[i][j] = fmaf(aq[i], bj[j], acc[i][j]);
    }

    #pragma unroll
    for (int ch=0; ch<4; ++ch) {
      if ((jg>>2) == ch) {
        const int cb = (jg&3)*16;
        #pragma unroll
        for (int qi=0;qi<8;++qi) {
          const int q = qg*8+qi;
          const float xq2 = s_x2q[q];
          #pragma unroll
          for (int jq=0;jq<4;++jq) {
            float4 v;
            v.x = xq2 + s_x2j[jg*16+jq*4+0] - 2.f*acc[qi][jq*4+0];
            v.y = xq2 + s_x2j[jg*16+jq*4+1] - 2.f*acc[qi][jq*4+1];
            v.z = xq2 + s_x2j[jg*16+jq*4+2] - 2.f*acc[qi][jq*4+2];
            v.w = xq2 + s_x2j[jg*16+jq*4+3] - 2.f*acc[qi][jq*4+3];
            *(float4*)&dch[q][cb + jq*4] = v;
          }
        }
      }
      __syncthreads();
      {
        const int jb = j0 + ch*64 + th*32;
        #pragma unroll
        for (int r4=0;r4<8;++r4) {
          float4 dv = *(const float4*)&dch[tq][th*32 + r4*4];
          float dd[4] = {dv.x, dv.y, dv.z, dv.w};
          #pragma unroll
          for (int u=0;u<4;++u) {
            float d = dd[u]; int jj = jb + r4*4 + u;
            if (lexless(d, jj, bd[9], bi[9])) {
              bd[9] = d; bi[9] = jj;
              #pragma unroll
              for (int s=8;s>=0;--s) {
                if (lexless(bd[s+1], bi[s+1], bd[s], bi[s])) {
                  float td = bd[s]; bd[s] = bd[s+1]; bd[s+1] = td;
                  int ti = bi[s]; bi[s] = bi[s+1]; bi[s+1] = ti;
                }
              }
            }
          }
        }
      }
      __syncthreads();
    }
  }

  #pragma unroll
  for (int u=0;u<10;++u) {
    dch[tq][th*10+u]    = bd[u];
    dch[tq][20+th*10+u] = __int_as_float(bi[u]);
  }
  __syncthreads();
  if (tid < 128) {
    int ia=0, ib2=0;
    int res[10];
    #pragma unroll
    for (int u=0;u<10;++u) {
      float da = dch[tid][ia],  db = dch[tid][10+ib2];
      int   ja = __float_as_int(dch[tid][20+ia]);
      int   jb = __float_as_int(dch[tid][30+ib2]);
      bool ta = lexless(da, ja, db, jb);
      res[u] = ta ? ja : jb;
      ia += ta ? 1 : 0; ib2 += ta ? 0 : 1;
    }
    int* op = idxout + ((size_t)b*NPTS + q0 + tid)*KNNK;
    #pragma unroll
    for (int u=0;u<10;++u) op[u] = res[u];
  }
}

// ---------- EdgeConv 1 (targets, 12->64->64, max over k) ----------
__global__ __launch_bounds__(256) void conv12_kernel(const float* __restrict__ T,
                                                     const int* __restrict__ idx,
                                                     const float* __restrict__ W1,
                                                     const float* __restrict__ W2,
                                                     const float* __restrict__ PA,
                                                     float* __restrict__ xcat){
  int gid = blockIdx.x*256 + threadIdx.x;
  int p = gid >> 1, kh = gid & 1, b = p >> 13;
  float a1 = PA[0], a2 = PA[1];
  float t0 = T[p*3+0], t1 = T[p*3+1], t2 = T[p*3+2];
  int nbk[5];
  #pragma unroll
  for (int k=0;k<5;++k) nbk[k] = idx[p*10 + kh*5 + k];
  float u0[5], u1[5], u2[5];
  #pragma unroll
  for (int k=0;k<5;++k) {
    const float* tn = T + ((size_t)(b<<13) + nbk[k])*3;
    u0[k]=tn[0]; u1[k]=tn[1]; u2[k]=tn[2];
  }
  const float4* W1f = (const float4*)W1;
  const float4* W2f = (const float4*)W2;
  float4 mx[16];
  #pragma unroll
  for (int o4=0;o4<16;++o4) mx[o4] = make_float4(-INFINITY,-INFINITY,-INFINITY,-INFINITY);
  for (int k=0;k<5;++k) {
    float e0=u0[k]-t0, e1=u1[k]-t1, e2=u2[k]-t2;
    float h[64];
    #pragma unroll
    for (int o4=0;o4<16;++o4) {
      float4 s = f4fma(e0, f4add(W1f[0*16+o4], W1f[3*16+o4]), make_float4(0,0,0,0));
      s = f4fma(e1, f4add(W1f[1*16+o4], W1f[4*16+o4]), s);
      s = f4fma(e2, f4add(W1f[2*16+o4], W1f[5*16+o4]), s);
      s = f4fma(t0, f4add(W1f[6*16+o4], W1f[9*16+o4]), s);
      s = f4fma(t1, f4add(W1f[7*16+o4], W1f[10*16+o4]), s);
      s = f4fma(t2, f4add(W1f[8*16+o4], W1f[11*16+o4]), s);
      h[o4*4+0]=preluf(s.x,a1); h[o4*4+1]=preluf(s.y,a1);
      h[o4*4+2]=preluf(s.z,a1); h[o4*4+3]=preluf(s.w,a1);
    }
    #pragma unroll
    for (int half=0; half<2; ++half) {
      float4 accB[8];
      #pragma unroll
      for (int o4=0;o4<8;++o4) accB[o4] = make_float4(0,0,0,0);
      #pragma unroll
      for (int c=0;c<64;++c) {
        const float hc = h[c];
        #pragma unroll
        for (int o4=0;o4<8;++o4) accB[o4] = f4fma(hc, W2f[c*16 + half*8 + o4], accB[o4]);
      }
      #pragma unroll
      for (int o4=0;o4<8;++o4) {
        int oo = half*8+o4;
        mx[oo].x = fmaxf(mx[oo].x, preluf(accB[o4].x,a2));
        mx[oo].y = fmaxf(mx[oo].y, preluf(accB[o4].y,a2));
        mx[oo].z = fmaxf(mx[oo].z, preluf(accB[o4].z,a2));
        mx[oo].w = fmaxf(mx[oo].w, preluf(accB[o4].w,a2));
      }
    }
  }
  #pragma unroll
  for (int o4=0;o4<16;++o4) {
    mx[o4].x = fmaxf(mx[o4].x, __shfl_xor(mx[o4].x, 1));
    mx[o4].y = fmaxf(mx[o4].y, __shfl_xor(mx[o4].y, 1));
    mx[o4].z = fmaxf(mx[o4].z, __shfl_xor(mx[o4].z, 1));
    mx[o4].w = fmaxf(mx[o4].w, __shfl_xor(mx[o4].w, 1));
  }
  if (kh == 0) {
    float4* dst = (float4*)(xcat + (size_t)p*192);
    #pragma unroll
    for (int o4=0;o4<16;++o4) dst[o4] = mx[o4];
  }
}

// ---------- EdgeConv generic (Cin=64; TWO=1 -> 128->64->64, TWO=0 -> 128->64) ----------
template<int TWO>
__global__ __launch_bounds__(256) void convG_kernel(const float* __restrict__ XC, int cin, int cout,
                                                    const int* __restrict__ idx,
                                                    const float* __restrict__ Wa,
                                                    const float* __restrict__ Wb,
                                                    const float* __restrict__ PA, int pbase,
                                                    float* __restrict__ XCout){
  __shared__ float smx[64][256];
  const int tid = threadIdx.x;
  const int gid = blockIdx.x*256 + tid;
  const int p = gid >> 1, kh = gid & 1, b = p >> 13;
  const float aa = PA[pbase];
  const float ab = TWO ? PA[pbase+1] : 0.f;
  float xi[64];
  {
    const float4* xr = (const float4*)(XC + (size_t)p*192 + cin);
    #pragma unroll
    for (int c4=0;c4<16;++c4){
      float4 v = xr[c4];
      xi[c4*4]=v.x; xi[c4*4+1]=v.y; xi[c4*4+2]=v.z; xi[c4*4+3]=v.w;
    }
  }
  #pragma unroll
  for (int o=0;o<64;++o) smx[o][tid] = -INFINITY;
  int nbk[5];
  #pragma unroll
  for (int k=0;k<5;++k) nbk[k] = idx[p*10 + kh*5 + k];
  const float4* Wa4 = (const float4*)Wa;
  const float4* Wb4 = (const float4*)Wb;
  for (int k=0;k<5;++k) {
    float e[64];
    {
      const float4* nr = (const float4*)(XC + ((size_t)(b<<13)+nbk[k])*192 + cin);
      #pragma unroll
      for (int c4=0;c4<16;++c4){
        float4 v = nr[c4];
        e[c4*4]=v.x-xi[c4*4]; e[c4*4+1]=v.y-xi[c4*4+1];
        e[c4*4+2]=v.z-xi[c4*4+2]; e[c4*4+3]=v.w-xi[c4*4+3];
      }
    }
    float h[64];
    #pragma unroll
    for (int half=0; half<2; ++half) {
      float4 accA[8];
      #pragma unroll
      for (int o4=0;o4<8;++o4) accA[o4] = make_float4(0,0,0,0);
      #pragma unroll
      for (int c=0;c<64;++c) {
        const float ec = e[c], xc = xi[c];
        #pragma unroll
        for (int o4=0;o4<8;++o4) {
          accA[o4] = f4fma(ec, Wa4[c*16 + half*8 + o4], accA[o4]);
          accA[o4] = f4fma(xc, Wa4[(64+c)*16 + half*8 + o4], accA[o4]);
        }
      }
      #pragma unroll
      for (int o4=0;o4<8;++o4) {
        float4 v = accA[o4];
        v.x = preluf(v.x,aa); v.y = preluf(v.y,aa); v.z = preluf(v.z,aa); v.w = preluf(v.w,aa);
        int o = (half*8+o4)*4;
        if (TWO) {
          h[o+0]=v.x; h[o+1]=v.y; h[o+2]=v.z; h[o+3]=v.w;
        } else {
          smx[o+0][tid] = fmaxf(smx[o+0][tid], v.x);
          smx[o+1][tid] = fmaxf(smx[o+1][tid], v.y);
          smx[o+2][tid] = fmaxf(smx[o+2][tid], v.z);
          smx[o+3][tid] = fmaxf(smx[o+3][tid], v.w);
        }
      }
    }
    if (TWO) {
      #pragma unroll
      for (int half=0; half<2; ++half) {
        float4 accB[8];
        #pragma unroll
        for (int o4=0;o4<8;++o4) accB[o4] = make_float4(0,0,0,0);
        #pragma unroll
        for (int c=0;c<64;++c) {
          const float hc = h[c];
          #pragma unroll
          for (int o4=0;o4<8;++o4) accB[o4] = f4fma(hc, Wb4[c*16 + half*8 + o4], accB[o4]);
        }
        #pragma unroll
        for (int o4=0;o4<8;++o4) {
          int o = (half*8+o4)*4;
          smx[o+0][tid] = fmaxf(smx[o+0][tid], preluf(accB[o4].x,ab));
          smx[o+1][tid] = fmaxf(smx[o+1][tid], preluf(accB[o4].y,ab));
          smx[o+2][tid] = fmaxf(smx[o+2][tid], preluf(accB[o4].z,ab));
          smx[o+3][tid] = fmaxf(smx[o+3][tid], preluf(accB[o4].w,ab));
        }
      }
    }
  }
  __syncthreads();
  if (kh == 0) {
    float4* dst = (float4*)(XCout + (size_t)p*192 + cout);
    #pragma unroll
    for (int o4=0;o4<16;++o4) {
      float4 v;
      v.x = fmaxf(smx[o4*4+0][tid], smx[o4*4+0][tid+1]);
      v.y = fmaxf(smx[o4*4+1][tid], smx[o4*4+1][tid+1]);
      v.z = fmaxf(smx[o4*4+2][tid], smx[o4*4+2][tid+1]);
      v.w = fmaxf(smx[o4*4+3][tid], smx[o4*4+3][tid+1]);
      dst[o4] = v;
    }
  }
}

// ---------- tiled fp32 GEMM: C = prelu(A@B [+bias]) ; EPI2: column-max partials ----------
template<int EPI>   // 0: prelu->store, 1: +bias prelu->store, 2: prelu->colmax partial
__global__ __launch_bounds__(256) void gemm_kernel(const float* __restrict__ A, int lda,
                                                   const float* __restrict__ Bm, int ldb,
                                                   float* __restrict__ C, int ldc,
                                                   const float* __restrict__ bias,
                                                   const float* __restrict__ PA, int pidx,
                                                   int K, int Ntot){
  __shared__ __align__(16) float As[16][132];
  __shared__ __align__(16) float Bs[16][132];
  const int tid = threadIdx.x;
  const int m0 = blockIdx.x*128, n0 = blockIdx.y*128;
  const int tm = tid & 15, tn = tid >> 4;
  float acc[8][8];
  #pragma unroll
  for (int i=0;i<8;++i)
    #pragma unroll
    for (int j=0;j<8;++j) acc[i][j]=0.f;

  for (int k0=0;k0<K;k0+=16) {
    {
      int r = tid >> 2, kq = (tid&3)*4;
      #pragma unroll
      for (int it=0; it<2; ++it) {
        int rr = r + it*64;
        float4 v = *(const float4*)(A + (size_t)(m0+rr)*lda + k0 + kq);
        As[kq+0][rr]=v.x; As[kq+1][rr]=v.y; As[kq+2][rr]=v.z; As[kq+3][rr]=v.w;
      }
    }
    {
      int kk = tid >> 4, c = (tid&15)*8;
      const float* bp = Bm + (size_t)(k0+kk)*ldb + n0 + c;
      *(float4*)&Bs[kk][c]   = *(const float4*)bp;
      *(float4*)&Bs[kk][c+4] = *(const float4*)(bp+4);
    }
    __syncthreads();
    #pragma unroll
    for (int kk=0;kk<16;++kk) {
      float av[8], bv[8];
      *(float4*)&av[0] = *(const float4*)&As[kk][tm*8+0];
      *(float4*)&av[4] = *(const float4*)&As[kk][tm*8+4];
      *(float4*)&bv[0] = *(const float4*)&Bs[kk][tn*8+0];
      *(float4*)&bv[4] = *(const float4*)&Bs[kk][tn*8+4];
      #pragma unroll
      for (int i=0;i<8;++i)
        #pragma unroll
        for (int j=0;j<8;++j)
          acc[i][j] = fmaf(av[i], bv[j], acc[i][j]);
    }
    __syncthreads();
  }
  const float a = PA[pidx];
  if (EPI == 2) {
    #pragma unroll
    for (int j=0;j<8;++j) {
      float m = -INFINITY;
      #pragma unroll
      for (int i=0;i<8;++i) { float v = acc[i][j]; v = v>=0.f? v : a*v; m = fmaxf(m,v); }
      #pragma unroll
      for (int off=1;off<16;off<<=1) m = fmaxf(m, __shfl_xor(m, off));
      if (tm == 0) C[(size_t)blockIdx.x*Ntot + n0 + tn*8 + j] = m;
    }
  } else {
    float bcol[8];
    if (EPI==1) {
      int bb = m0 >> 13;
      #pragma unroll
      for (int j=0;j<8;++j) bcol[j] = bias[bb*256 + n0 + tn*8 + j];
    }
    #pragma unroll
    for (int i=0;i<8;++i) {
      float out[8];
      #pragma unroll
      for (int j=0;j<8;++j) {
        float v = acc[i][j] + (EPI==1 ? bcol[j] : 0.f);
        out[j] = v>=0.f? v : a*v;
      }
      float* cp = C + (size_t)(m0 + tm*8 + i)*ldc + n0 + tn*8;
      *(float4*)cp     = make_float4(out[0],out[1],out[2],out[3]);
      *(float4*)(cp+4) = make_float4(out[4],out[5],out[6],out[7]);
    }
  }
}

__global__ __launch_bounds__(256) void reduce_pmax(const float* __restrict__ pmax,
                                                   float* __restrict__ x5m){
  int t = blockIdx.x*256 + threadIdx.x;
  if (t < 4096) {
    int b = t >> 10, o = t & 1023;
    float m = -INFINITY;
    for (int mt=0; mt<64; ++mt) m = fmaxf(m, pmax[((size_t)(b*64+mt))*1024 + o]);
    x5m[t] = m;
  }
}

__global__ __launch_bounds__(256) void bias7_kernel(const float* __restrict__ x5m,
                                                    const float* __restrict__ W7,
                                                    float* __restrict__ b7){
  int b = blockIdx.x; int o = threadIdx.x;
  float s = 0.f;
  for (int j=0;j<1024;++j) s = fmaf(x5m[b*1024+j], W7[(size_t)(192+j)*256 + o], s);
  b7[b*256+o] = s;
}

__global__ __launch_bounds__(256) void final10_kernel(const float* __restrict__ y3,
                                                      const float* __restrict__ W10,
                                                      const float* __restrict__ PA,
                                                      float* __restrict__ out){
  int p = blockIdx.x*256 + threadIdx.x;
  const float4* r = (const float4*)(y3 + (size_t)p*128);
  float s0=0.f, s1=0.f;
  #pragma unroll
  for (int c4=0;c4<32;++c4){
    float4 v = r[c4];
    s0 = fmaf(v.x, W10[(c4*4+0)*2+0], s0); s1 = fmaf(v.x, W10[(c4*4+0)*2+1], s1);
    s0 = fmaf(v.y, W10[(c4*4+1)*2+0], s0); s1 = fmaf(v.y, W10[(c4*4+1)*2+1], s1);
    s0 = fmaf(v.z, W10[(c4*4+2)*2+0], s0); s1 = fmaf(v.z, W10[(c4*4+2)*2+1], s1);
    s0 = fmaf(v.w, W10[(c4*4+3)*2+0], s0); s1 = fmaf(v.w, W10[(c4*4+3)*2+1], s1);
  }
  float a = PA[9];
  out[p*2+0] = s0>=0.f? s0 : a*s0;
  out[p*2+1] = s1>=0.f? s1 : a*s1;
}

extern "C" void kernel_launch(void* const* d_in, const int* in_sizes, int n_in,
                              void* d_out, int out_size, void* d_ws, size_t ws_size,
                              hipStream_t stream) {
  const float* T   = (const float*)d_in[0];
  const float* W1  = (const float*)d_in[1];
  const float* W2  = (const float*)d_in[2];
  const float* W3  = (const float*)d_in[3];
  const float* W4  = (const float*)d_in[4];
  const float* W5  = (const float*)d_in[5];
  const float* W6  = (const float*)d_in[6];
  const float* W7  = (const float*)d_in[7];
  const float* W8  = (const float*)d_in[8];
  const float* W9  = (const float*)d_in[9];
  const float* W10 = (const float*)d_in[10];
  const float* PA  = (const float*)d_in[11];

  float* ws   = (float*)d_ws;          // needs ~98.2 MB of workspace
  float* x0   = ws + 0;                // 131072
  float* sqn0 = ws + 131072;           // 32768
  float* sqn1 = ws + 163840;           // 32768
  float* sqn2 = ws + 196608;           // 32768
  int*   idx0 = (int*)(ws + 229376);   // 327680
  int*   idx1 = (int*)(ws + 557056);   // 327680
  int*   idx2 = (int*)(ws + 884736);   // 327680
  float* xcat = ws + 1212416;          // 6291456  [B,N,192]
  float* pmax = ws + 7503872;          // 262144
  float* x5m  = ws + 7766016;          // 4096
  float* b7   = ws + 7770112;          // 1024
  float* y1   = ws + 7771136;          // 8388608
  float* y2   = ws + 16159744;         // 8388608 -> end 24548352 floats
  float* y3   = xcat;                  // alias: xcat dead after mlp7

  prep0_kernel<<<128, 256, 0, stream>>>(T, x0, sqn0);
  knn_kernel<4><<<dim3(64,4), 256, 0, stream>>>(x0, 4, 0, sqn0, idx0);
  conv12_kernel<<<256, 256, 0, stream>>>(T, idx0, W1, W2, PA, xcat);

  sqnorm_kernel<<<128, 256, 0, stream>>>(xcat, 0, sqn1);
  knn_kernel<64><<<dim3(64,4), 256, 0, stream>>>(xcat, 192, 0, sqn1, idx1);
  convG_kernel<1><<<256, 256, 0, stream>>>(xcat, 0, 64, idx1, W3, W4, PA, 2, xcat);

  sqnorm_kernel<<<128, 256, 0, stream>>>(xcat, 64, sqn2);
  knn_kernel<64><<<dim3(64,4), 256, 0, stream>>>(xcat, 192, 64, sqn2, idx2);
  convG_kernel<0><<<256, 256, 0, stream>>>(xcat, 64, 128, idx2, W5, nullptr, PA, 4, xcat);

  // x5 = prelu(x4 @ W6), global max over N (per batch)
  gemm_kernel<2><<<dim3(256,8), 256, 0, stream>>>(xcat, 192, W6, 1024, pmax, 0, nullptr, PA, 5, 192, 1024);
  reduce_pmax<<<16, 256, 0, stream>>>(pmax, x5m);
  // fold x5max @ W7[192:] into per-batch bias
  bias7_kernel<<<4, 256, 0, stream>>>(x5m, W7, b7);
  gemm_kernel<1><<<dim3(256,2), 256, 0, stream>>>(xcat, 192, W7, 256, y1, 256, b7, PA, 6, 192, 256);
  gemm_kernel<0><<<dim3(256,2), 256, 0, stream>>>(y1, 256, W8, 256, y2, 256, nullptr, PA, 7, 256, 256);
  gemm_kernel<0><<<dim3(256,1), 256, 0, stream>>>(y2, 256, W9, 128, y3, 128, nullptr, PA, 8, 256, 128);
  final10_kernel<<<128, 256, 0, stream>>>(y3, W10, PA, (float*)d_out);
}